// Round 1
// baseline (570.306 us; speedup 1.0000x reference)
//
#include <hip/hip_runtime.h>

#define N_NODES 50000
#define E_EDGES 640000
#define D 128
#define DS 64

// ---------------- CSR build ----------------

__global__ void degree_kernel(const int* __restrict__ dst, int* __restrict__ deg, int e) {
    int i = blockIdx.x * blockDim.x + threadIdx.x;
    if (i < e) atomicAdd(&deg[dst[i]], 1);
}

__global__ void scan_kernel(const int* __restrict__ deg, int* __restrict__ rowptr, int n) {
    __shared__ int sm[1024];
    __shared__ int carry;
    int tid = threadIdx.x;
    if (tid == 0) carry = 0;
    __syncthreads();
    for (int base = 0; base < n; base += 1024) {
        int v = (base + tid < n) ? deg[base + tid] : 0;
        sm[tid] = v;
        __syncthreads();
        for (int off = 1; off < 1024; off <<= 1) {
            int t = (tid >= off) ? sm[tid - off] : 0;
            __syncthreads();
            sm[tid] += t;
            __syncthreads();
        }
        if (base + tid < n) rowptr[base + tid] = carry + sm[tid] - v;  // exclusive
        __syncthreads();
        if (tid == 0) carry += sm[1023];
        __syncthreads();
    }
    if (tid == 0) rowptr[n] = carry;
}

__global__ void copy_kernel(const int* __restrict__ a, int* __restrict__ b, int n) {
    int i = blockIdx.x * blockDim.x + threadIdx.x;
    if (i < n) b[i] = a[i];
}

__global__ void fill_kernel(const int* __restrict__ src, const int* __restrict__ dst,
                            int* __restrict__ cursor, int* __restrict__ esrc, int e) {
    int i = blockIdx.x * blockDim.x + threadIdx.x;
    if (i < e) {
        int pos = atomicAdd(&cursor[dst[i]], 1);
        esrc[pos] = src[i];
    }
}

// ---------------- segment mean (one wave per dst node) ----------------

__global__ void aggregate_mean(const float* __restrict__ feat, const int* __restrict__ rowptr,
                               const int* __restrict__ esrc, float* __restrict__ mean, int n) {
    int wid = threadIdx.x >> 6;           // 4 waves per block
    int lane = threadIdx.x & 63;
    int d = blockIdx.x * 4 + wid;
    if (d >= n) return;
    int beg = rowptr[d], end = rowptr[d + 1];
    float2 acc = make_float2(0.f, 0.f);
    for (int i = beg; i < end; ++i) {
        int s = esrc[i];
        float2 v = ((const float2*)(feat + (size_t)s * D))[lane];
        acc.x += v.x; acc.y += v.y;
    }
    float inv = (end > beg) ? 1.0f / (float)(end - beg) : 0.0f;
    acc.x *= inv; acc.y *= inv;
    ((float2*)(mean + (size_t)d * D))[lane] = acc;
}

// ---------------- fused SAGE linear: H = [relu](mean@Wl + b + self@Wr), opt OutS = H@Ws ----------------

template <bool RELU, bool OUTS>
__global__ __launch_bounds__(128) void sage_gemm(
    const float* __restrict__ Amean, const float* __restrict__ Aself,
    const float* __restrict__ Wl, const float* __restrict__ Wr,
    const float* __restrict__ b, float* __restrict__ H,
    const float* __restrict__ Ws, float* __restrict__ OutS, int n)
{
    const int R = 16;
    __shared__ float smean[R][D];
    __shared__ float sself[R][D];
    int j = threadIdx.x;                  // output column 0..127
    int row0 = blockIdx.x * R;

    for (int r = 0; r < R; ++r) {
        int row = row0 + r;
        int rc = row < n ? row : n - 1;
        smean[r][j] = Amean[(size_t)rc * D + j];
        sself[r][j] = Aself[(size_t)rc * D + j];
    }
    __syncthreads();

    float acc[R];
    float bj = b[j];
#pragma unroll
    for (int r = 0; r < R; ++r) acc[r] = bj;

#pragma unroll 4
    for (int k = 0; k < D; ++k) {
        float wl = Wl[k * D + j];
        float wr = Wr[k * D + j];
#pragma unroll
        for (int r = 0; r < R; ++r)
            acc[r] += smean[r][k] * wl + sself[r][k] * wr;
    }

    if (RELU) {
#pragma unroll
        for (int r = 0; r < R; ++r) acc[r] = fmaxf(acc[r], 0.0f);
    }

#pragma unroll
    for (int r = 0; r < R; ++r) {
        int row = row0 + r;
        if (row < n) H[(size_t)row * D + j] = acc[r];
    }

    if (OUTS) {
        __syncthreads();                  // done reading smean
#pragma unroll
        for (int r = 0; r < R; ++r) smean[r][j] = acc[r];   // reuse as h2 tile
        __syncthreads();
        int m = j & 63;
        int half = j >> 6;
        for (int t = 0; t < 8; ++t) {
            int r = (t << 1) | half;
            int row = row0 + r;
            float s = 0.f;
#pragma unroll 4
            for (int k = 0; k < D; ++k) s += smean[r][k] * Ws[k * DS + m];
            if (row < n) OutS[(size_t)row * DS + m] = s;
        }
    }
}

extern "C" void kernel_launch(void* const* d_in, const int* in_sizes, int n_in,
                              void* d_out, int out_size, void* d_ws, size_t ws_size,
                              hipStream_t stream) {
    const float* x   = (const float*)d_in[0];
    const int*   ei  = (const int*)d_in[1];
    const float* Wl1 = (const float*)d_in[2];
    const float* bl1 = (const float*)d_in[3];
    const float* Wr1 = (const float*)d_in[4];
    const float* Wl2 = (const float*)d_in[5];
    const float* bl2 = (const float*)d_in[6];
    const float* Wr2 = (const float*)d_in[7];
    const float* Ws  = (const float*)d_in[8];

    const int* src = ei;              // edge_index[0]
    const int* dst = ei + E_EDGES;    // edge_index[1]

    char* wsb = (char*)d_ws;
    size_t off = 0;
    auto alloc = [&](size_t bytes) -> void* {
        void* p = wsb + off;
        off = (off + bytes + 255) & ~(size_t)255;
        return p;
    };
    int*   rowptr = (int*)alloc(4 * (size_t)(N_NODES + 1));
    int*   deg    = (int*)alloc(4 * (size_t)N_NODES);
    int*   cursor = (int*)alloc(4 * (size_t)N_NODES);
    int*   esrc   = (int*)alloc(4 * (size_t)E_EDGES);
    float* mean   = (float*)alloc(4 * (size_t)N_NODES * D);
    float* h1     = (float*)alloc(4 * (size_t)N_NODES * D);

    float* out_s = (float*)d_out;
    float* h2    = (float*)d_out + (size_t)N_NODES * DS;

    // CSR build (same graph for both layers)
    hipMemsetAsync(deg, 0, 4 * (size_t)N_NODES, stream);
    degree_kernel<<<(E_EDGES + 255) / 256, 256, 0, stream>>>(dst, deg, E_EDGES);
    scan_kernel<<<1, 1024, 0, stream>>>(deg, rowptr, N_NODES);
    copy_kernel<<<(N_NODES + 255) / 256, 256, 0, stream>>>(rowptr, cursor, N_NODES);
    fill_kernel<<<(E_EDGES + 255) / 256, 256, 0, stream>>>(src, dst, cursor, esrc, E_EDGES);

    // layer 1
    aggregate_mean<<<(N_NODES + 3) / 4, 256, 0, stream>>>(x, rowptr, esrc, mean, N_NODES);
    sage_gemm<true, false><<<(N_NODES + 15) / 16, 128, 0, stream>>>(
        mean, x, Wl1, Wr1, bl1, h1, nullptr, nullptr, N_NODES);

    // layer 2 (+ fused out_s)
    aggregate_mean<<<(N_NODES + 3) / 4, 256, 0, stream>>>(h1, rowptr, esrc, mean, N_NODES);
    sage_gemm<false, true><<<(N_NODES + 15) / 16, 128, 0, stream>>>(
        mean, h1, Wl2, Wr2, bl2, h2, Ws, out_s, N_NODES);
}

// Round 2
// 348.979 us; speedup vs baseline: 1.6342x; 1.6342x over previous
//
#include <hip/hip_runtime.h>

#define N_NODES 50000
#define E_EDGES 640000
#define D 128
#define DS 64

typedef __bf16 bf16x8 __attribute__((ext_vector_type(8)));
typedef float f32x4 __attribute__((ext_vector_type(4)));

static __device__ __forceinline__ ushort f2bf(float f) {
    uint u = __float_as_uint(f);
    uint r = u + 0x7fffu + ((u >> 16) & 1u);
    return (ushort)(r >> 16);
}

// ---------------- CSR build ----------------

__global__ void degree_kernel(const int* __restrict__ dst, int* __restrict__ deg, int e) {
    int i = blockIdx.x * blockDim.x + threadIdx.x;
    if (i < e) atomicAdd(&deg[dst[i]], 1);
}

__global__ void scan_kernel(const int* __restrict__ deg, int* __restrict__ rowptr, int n) {
    __shared__ int sm[1024];
    __shared__ int carry;
    int tid = threadIdx.x;
    if (tid == 0) carry = 0;
    __syncthreads();
    for (int base = 0; base < n; base += 1024) {
        int v = (base + tid < n) ? deg[base + tid] : 0;
        sm[tid] = v;
        __syncthreads();
        for (int off = 1; off < 1024; off <<= 1) {
            int t = (tid >= off) ? sm[tid - off] : 0;
            __syncthreads();
            sm[tid] += t;
            __syncthreads();
        }
        if (base + tid < n) rowptr[base + tid] = carry + sm[tid] - v;  // exclusive
        __syncthreads();
        if (tid == 0) carry += sm[1023];
        __syncthreads();
    }
    if (tid == 0) rowptr[n] = carry;
}

__global__ void copy_kernel(const int* __restrict__ a, int* __restrict__ b, int n) {
    int i = blockIdx.x * blockDim.x + threadIdx.x;
    if (i < n) b[i] = a[i];
}

__global__ void fill_kernel(const int* __restrict__ src, const int* __restrict__ dst,
                            int* __restrict__ cursor, int* __restrict__ esrc, int e) {
    int i = blockIdx.x * blockDim.x + threadIdx.x;
    if (i < e) {
        int pos = atomicAdd(&cursor[dst[i]], 1);
        esrc[pos] = src[i];
    }
}

// ---------------- conversions ----------------

__global__ void f32_to_bf16_kernel(const float* __restrict__ in, ushort* __restrict__ out, int n4) {
    int i = blockIdx.x * blockDim.x + threadIdx.x;
    int stride = gridDim.x * blockDim.x;
    for (; i < n4; i += stride) {
        float4 v = ((const float4*)in)[i];
        ushort4 o;
        o.x = f2bf(v.x); o.y = f2bf(v.y); o.z = f2bf(v.z); o.w = f2bf(v.w);
        ((ushort4*)out)[i] = o;
    }
}

// WT1[n][k] (k<128: Wl1[k][n], else Wr1[k-128][n]); WT2 same; WsT[m][k] = Ws[k][m]
__global__ void transpose_weights(const float* __restrict__ Wl1, const float* __restrict__ Wr1,
                                  const float* __restrict__ Wl2, const float* __restrict__ Wr2,
                                  const float* __restrict__ Ws,
                                  ushort* __restrict__ WT1, ushort* __restrict__ WT2,
                                  ushort* __restrict__ WsT) {
    int i = blockIdx.x * blockDim.x + threadIdx.x;
    if (i < 32768) {
        int n = i >> 8, k = i & 255;
        float v = (k < 128) ? Wl1[k * 128 + n] : Wr1[(k - 128) * 128 + n];
        WT1[i] = f2bf(v);
    } else if (i < 65536) {
        int j = i - 32768;
        int n = j >> 8, k = j & 255;
        float v = (k < 128) ? Wl2[k * 128 + n] : Wr2[(k - 128) * 128 + n];
        WT2[j] = f2bf(v);
    } else if (i < 73728) {
        int j = i - 65536;
        int m = j >> 7, k = j & 127;
        WsT[j] = f2bf(Ws[k * 64 + m]);
    }
}

// ---------------- segment mean, bf16 in/out (one wave per dst node) ----------------

__global__ void aggregate_mean_bf16(const ushort* __restrict__ feat, const int* __restrict__ rowptr,
                                    const int* __restrict__ esrc, ushort* __restrict__ mean, int n) {
    int wid = threadIdx.x >> 6;           // 4 waves per block
    int lane = threadIdx.x & 63;
    int d = blockIdx.x * 4 + wid;
    if (d >= n) return;
    int beg = rowptr[d], end = rowptr[d + 1];
    float ax = 0.f, ay = 0.f;
    int i = beg;
    while (i < end) {
        int cnt = end - i; if (cnt > 64) cnt = 64;
        int e = (lane < cnt) ? esrc[i + lane] : 0;
        for (int t = 0; t < cnt; ++t) {
            int s = __shfl(e, t);
            uint v = ((const uint*)(feat + (size_t)s * D))[lane];
            ax += __uint_as_float(v << 16);
            ay += __uint_as_float(v & 0xffff0000u);
        }
        i += cnt;
    }
    float inv = (end > beg) ? 1.0f / (float)(end - beg) : 0.0f;
    uint lo = (uint)f2bf(ax * inv);
    uint hi = (uint)f2bf(ay * inv);
    ((uint*)(mean + (size_t)d * D))[lane] = lo | (hi << 16);
}

// ---------------- fused SAGE MFMA GEMM: C = [mean|self] @ WT^T + b ----------------
// 4 waves, BM=64, each wave owns 16 rows x 128 cols. K=256 (two 128-col sources).
// A staged to LDS via global_load_lds w/ XOR swizzle (linear dest, inv-swz source).

template <bool RELU, bool WF32, bool WBF16>
__global__ __launch_bounds__(256) void sage_mfma(
    const ushort* __restrict__ A1, const ushort* __restrict__ A2,
    const ushort* __restrict__ WT, const float* __restrict__ bias,
    float* __restrict__ Hf, ushort* __restrict__ Hb, int M)
{
    __shared__ __attribute__((aligned(16))) char smem[64 * 512];  // 32 KB: [64 rows][512 B]
    int w = threadIdx.x >> 6, lane = threadIdx.x & 63;
    int row0 = blockIdx.x * 64;

    // each wave stages its own 16 rows (8 KB), 1024 B per iteration
#pragma unroll
    for (int it = 0; it < 8; ++it) {
        int off = w * 8192 + it * 1024 + lane * 16;   // linear LDS byte offset
        int row = off >> 9;
        int colb = off & 511;
        int csrc = colb ^ ((row & 7) << 4);           // inverse-swizzled source col
        int rg = row0 + row; if (rg > M - 1) rg = M - 1;
        const char* src = (csrc < 256)
            ? (const char*)A1 + (size_t)rg * 256 + csrc
            : (const char*)A2 + (size_t)rg * 256 + (csrc - 256);
        __builtin_amdgcn_global_load_lds(
            (const __attribute__((address_space(1))) void*)src,
            (__attribute__((address_space(3))) void*)(smem + w * 8192 + it * 1024),
            16, 0, 0);
    }
    asm volatile("s_waitcnt vmcnt(0)" ::: "memory");   // own-wave data only; no barrier needed

    // A fragments: lane holds A[row = lane&15][k = s*32 + (lane>>4)*8 .. +8]
    bf16x8 a[8];
#pragma unroll
    for (int s = 0; s < 8; ++s) {
        int lin = (w * 16 + (lane & 15)) * 512 + s * 64 + (lane >> 4) * 16;
        int adr = lin ^ ((lane & 7) << 4);            // row&7 == lane&7 (w*16 % 8 == 0)
        a[s] = *reinterpret_cast<const bf16x8*>(smem + adr);
    }

    f32x4 acc[8];
#pragma unroll
    for (int f = 0; f < 8; ++f) acc[f] = (f32x4){0.f, 0.f, 0.f, 0.f};

#pragma unroll
    for (int s = 0; s < 8; ++s) {
#pragma unroll
        for (int f = 0; f < 8; ++f) {
            // B fragment: lane holds WT[col = f*16 + (lane&15)][k = s*32 + (lane>>4)*8 .. +8]
            const ushort* bp = WT + ((f * 16 + (lane & 15)) * 256 + s * 32 + (lane >> 4) * 8);
            bf16x8 b = *reinterpret_cast<const bf16x8*>(bp);
            acc[f] = __builtin_amdgcn_mfma_f32_16x16x32_bf16(a[s], b, acc[f], 0, 0, 0);
        }
    }

    // epilogue: C col = lane&15 (+16f), row = (lane>>4)*4 + r
    int colbase = lane & 15;
    int rquad = lane >> 4;
#pragma unroll
    for (int f = 0; f < 8; ++f) {
        int col = f * 16 + colbase;
        float bj = bias[col];
#pragma unroll
        for (int r = 0; r < 4; ++r) {
            int row = row0 + w * 16 + rquad * 4 + r;
            if (row < M) {
                float v = acc[f][r] + bj;
                if (RELU) v = fmaxf(v, 0.f);
                if (WF32) Hf[(size_t)row * 128 + col] = v;
                if (WBF16) Hb[(size_t)row * 128 + col] = f2bf(v);
            }
        }
    }
}

// ---------------- out_s = h2b @ Ws  (M x 128 @ 128 x 64) ----------------

__global__ __launch_bounds__(256) void out_mfma(
    const ushort* __restrict__ A, const ushort* __restrict__ WsT,
    float* __restrict__ Out, int M)
{
    __shared__ __attribute__((aligned(16))) char smem[64 * 256];  // 16 KB
    int w = threadIdx.x >> 6, lane = threadIdx.x & 63;
    int row0 = blockIdx.x * 64;

#pragma unroll
    for (int it = 0; it < 4; ++it) {
        int off = w * 4096 + it * 1024 + lane * 16;
        int row = off >> 8;
        int colb = off & 255;
        int csrc = colb ^ ((row & 7) << 4);
        int rg = row0 + row; if (rg > M - 1) rg = M - 1;
        __builtin_amdgcn_global_load_lds(
            (const __attribute__((address_space(1))) void*)((const char*)A + (size_t)rg * 256 + csrc),
            (__attribute__((address_space(3))) void*)(smem + w * 4096 + it * 1024),
            16, 0, 0);
    }
    asm volatile("s_waitcnt vmcnt(0)" ::: "memory");

    bf16x8 a[4];
#pragma unroll
    for (int s = 0; s < 4; ++s) {
        int lin = (w * 16 + (lane & 15)) * 256 + s * 64 + (lane >> 4) * 16;
        int adr = lin ^ ((lane & 7) << 4);
        a[s] = *reinterpret_cast<const bf16x8*>(smem + adr);
    }

    f32x4 acc[4];
#pragma unroll
    for (int f = 0; f < 4; ++f) acc[f] = (f32x4){0.f, 0.f, 0.f, 0.f};

#pragma unroll
    for (int s = 0; s < 4; ++s) {
#pragma unroll
        for (int f = 0; f < 4; ++f) {
            const ushort* bp = WsT + ((f * 16 + (lane & 15)) * 128 + s * 32 + (lane >> 4) * 8);
            bf16x8 b = *reinterpret_cast<const bf16x8*>(bp);
            acc[f] = __builtin_amdgcn_mfma_f32_16x16x32_bf16(a[s], b, acc[f], 0, 0, 0);
        }
    }

    int colbase = lane & 15;
    int rquad = lane >> 4;
#pragma unroll
    for (int f = 0; f < 4; ++f) {
        int col = f * 16 + colbase;
#pragma unroll
        for (int r = 0; r < 4; ++r) {
            int row = row0 + w * 16 + rquad * 4 + r;
            if (row < M) Out[(size_t)row * DS + col] = acc[f][r];
        }
    }
}

extern "C" void kernel_launch(void* const* d_in, const int* in_sizes, int n_in,
                              void* d_out, int out_size, void* d_ws, size_t ws_size,
                              hipStream_t stream) {
    const float* x   = (const float*)d_in[0];
    const int*   ei  = (const int*)d_in[1];
    const float* Wl1 = (const float*)d_in[2];
    const float* bl1 = (const float*)d_in[3];
    const float* Wr1 = (const float*)d_in[4];
    const float* Wl2 = (const float*)d_in[5];
    const float* bl2 = (const float*)d_in[6];
    const float* Wr2 = (const float*)d_in[7];
    const float* Ws  = (const float*)d_in[8];

    const int* src = ei;              // edge_index[0]
    const int* dst = ei + E_EDGES;    // edge_index[1]

    char* wsb = (char*)d_ws;
    size_t off = 0;
    auto alloc = [&](size_t bytes) -> void* {
        void* p = wsb + off;
        off = (off + bytes + 255) & ~(size_t)255;
        return p;
    };
    int*    rowptr = (int*)alloc(4 * (size_t)(N_NODES + 1));
    int*    deg    = (int*)alloc(4 * (size_t)N_NODES);
    int*    cursor = (int*)alloc(4 * (size_t)N_NODES);
    int*    esrc   = (int*)alloc(4 * (size_t)E_EDGES);
    ushort* xb     = (ushort*)alloc(2 * (size_t)N_NODES * D);
    ushort* meanb  = (ushort*)alloc(2 * (size_t)N_NODES * D);
    ushort* h1b    = (ushort*)alloc(2 * (size_t)N_NODES * D);
    ushort* h2b    = (ushort*)alloc(2 * (size_t)N_NODES * D);
    ushort* WT1    = (ushort*)alloc(2 * 128 * 256);
    ushort* WT2    = (ushort*)alloc(2 * 128 * 256);
    ushort* WsT    = (ushort*)alloc(2 * 64 * 128);

    float* out_s = (float*)d_out;
    float* h2    = (float*)d_out + (size_t)N_NODES * DS;

    // CSR build
    hipMemsetAsync(deg, 0, 4 * (size_t)N_NODES, stream);
    degree_kernel<<<(E_EDGES + 255) / 256, 256, 0, stream>>>(dst, deg, E_EDGES);
    scan_kernel<<<1, 1024, 0, stream>>>(deg, rowptr, N_NODES);
    copy_kernel<<<(N_NODES + 255) / 256, 256, 0, stream>>>(rowptr, cursor, N_NODES);
    fill_kernel<<<(E_EDGES + 255) / 256, 256, 0, stream>>>(src, dst, cursor, esrc, E_EDGES);

    // dtype prep
    f32_to_bf16_kernel<<<2048, 256, 0, stream>>>(x, xb, N_NODES * D / 4);
    transpose_weights<<<(73728 + 255) / 256, 256, 0, stream>>>(
        Wl1, Wr1, Wl2, Wr2, Ws, WT1, WT2, WsT);

    const int GB = (N_NODES + 63) / 64;   // 782 GEMM blocks

    // layer 1
    aggregate_mean_bf16<<<(N_NODES + 3) / 4, 256, 0, stream>>>(xb, rowptr, esrc, meanb, N_NODES);
    sage_mfma<true, false, true><<<GB, 256, 0, stream>>>(
        meanb, xb, WT1, bl1, nullptr, h1b, N_NODES);

    // layer 2
    aggregate_mean_bf16<<<(N_NODES + 3) / 4, 256, 0, stream>>>(h1b, rowptr, esrc, meanb, N_NODES);
    sage_mfma<false, true, true><<<GB, 256, 0, stream>>>(
        meanb, h1b, WT2, bl2, h2, h2b, N_NODES);

    // out_s
    out_mfma<<<GB, 256, 0, stream>>>(h2b, WsT, out_s, N_NODES);
}

// Round 3
// 248.054 us; speedup vs baseline: 2.2991x; 1.4069x over previous
//
#include <hip/hip_runtime.h>

#define N_NODES 50000
#define E_EDGES 640000
#define D 128
#define DS 64

typedef __bf16 bf16x8 __attribute__((ext_vector_type(8)));
typedef float f32x4 __attribute__((ext_vector_type(4)));

static __device__ __forceinline__ ushort f2bf(float f) {
    uint u = __float_as_uint(f);
    uint r = u + 0x7fffu + ((u >> 16) & 1u);
    return (ushort)(r >> 16);
}

// ---------------- segment build (no scan: disjoint segments via atomic allocator) ----------------

__global__ void degree_kernel(const int* __restrict__ dst, int* __restrict__ deg, int e) {
    int i = blockIdx.x * blockDim.x + threadIdx.x;
    if (i < e) atomicAdd(&deg[dst[i]], 1);
}

// start[i] = disjoint segment base (order unimportant); cursor[i] = start[i]
__global__ void assign_kernel(const int* __restrict__ deg, int* __restrict__ start,
                              int* __restrict__ cursor, int* __restrict__ counter, int n) {
    int i = blockIdx.x * blockDim.x + threadIdx.x;
    int lane = threadIdx.x & 63;
    int v = (i < n) ? deg[i] : 0;
    int s = v;
#pragma unroll
    for (int off = 1; off < 64; off <<= 1) {
        int t = __shfl_up(s, off);
        if (lane >= off) s += t;
    }
    int total = __shfl(s, 63);
    int base = 0;
    if (lane == 63) base = atomicAdd(counter, total);
    base = __shfl(base, 63);
    int ex = base + s - v;    // exclusive within wave
    if (i < n) { start[i] = ex; cursor[i] = ex; }
}

__global__ void fill_kernel(const int* __restrict__ src, const int* __restrict__ dst,
                            int* __restrict__ cursor, int* __restrict__ esrc, int e) {
    int i = blockIdx.x * blockDim.x + threadIdx.x;
    if (i < e) {
        int pos = atomicAdd(&cursor[dst[i]], 1);
        esrc[pos] = src[i];
    }
}

// ---------------- conversions ----------------

__global__ void f32_to_bf16_kernel(const float* __restrict__ in, ushort* __restrict__ out, int n4) {
    int i = blockIdx.x * blockDim.x + threadIdx.x;
    int stride = gridDim.x * blockDim.x;
    for (; i < n4; i += stride) {
        float4 v = ((const float4*)in)[i];
        ushort4 o;
        o.x = f2bf(v.x); o.y = f2bf(v.y); o.z = f2bf(v.z); o.w = f2bf(v.w);
        ((ushort4*)out)[i] = o;
    }
}

// WT1[n][k] (k<128: Wl1[k][n], else Wr1[k-128][n]); WT2 same; WsT[m][k] = Ws[k][m]
__global__ void transpose_weights(const float* __restrict__ Wl1, const float* __restrict__ Wr1,
                                  const float* __restrict__ Wl2, const float* __restrict__ Wr2,
                                  const float* __restrict__ Ws,
                                  ushort* __restrict__ WT1, ushort* __restrict__ WT2,
                                  ushort* __restrict__ WsT) {
    int i = blockIdx.x * blockDim.x + threadIdx.x;
    if (i < 32768) {
        int n = i >> 8, k = i & 255;
        float v = (k < 128) ? Wl1[k * 128 + n] : Wr1[(k - 128) * 128 + n];
        WT1[i] = f2bf(v);
    } else if (i < 65536) {
        int j = i - 32768;
        int n = j >> 8, k = j & 255;
        float v = (k < 128) ? Wl2[k * 128 + n] : Wr2[(k - 128) * 128 + n];
        WT2[j] = f2bf(v);
    } else if (i < 73728) {
        int j = i - 65536;
        int m = j >> 7, k = j & 127;
        WsT[j] = f2bf(Ws[k * 64 + m]);
    }
}

// ---------------- segment mean, bf16 in/out ----------------
// one wave per dst node; 16 lanes x 16B cover a 256B row; 4 edges in flight per iter

__global__ void aggregate_mean_bf16(const ushort* __restrict__ feat, const int* __restrict__ start,
                                    const int* __restrict__ deg, const int* __restrict__ esrc,
                                    ushort* __restrict__ mean, int n) {
    int wid = threadIdx.x >> 6;           // 4 waves per block
    int lane = threadIdx.x & 63;
    int d = blockIdx.x * 4 + wid;
    if (d >= n) return;
    int beg = start[d], cnt = deg[d];
    int g = lane >> 4;                    // edge group 0..3
    int gl = lane & 15;                   // 16B chunk within row

    float acc[8] = {0.f, 0.f, 0.f, 0.f, 0.f, 0.f, 0.f, 0.f};
    for (int i = 0; i < cnt; i += 4) {
        int idx = i + g;
        if (idx < cnt) {
            int e = esrc[beg + idx];
            uint4 v = ((const uint4*)(feat + (size_t)e * D))[gl];
            acc[0] += __uint_as_float(v.x << 16);
            acc[1] += __uint_as_float(v.x & 0xffff0000u);
            acc[2] += __uint_as_float(v.y << 16);
            acc[3] += __uint_as_float(v.y & 0xffff0000u);
            acc[4] += __uint_as_float(v.z << 16);
            acc[5] += __uint_as_float(v.z & 0xffff0000u);
            acc[6] += __uint_as_float(v.w << 16);
            acc[7] += __uint_as_float(v.w & 0xffff0000u);
        }
    }
    // reduce the 4 edge groups (lanes differing in bits 4,5)
#pragma unroll
    for (int m = 16; m <= 32; m <<= 1) {
#pragma unroll
        for (int j = 0; j < 8; ++j) acc[j] += __shfl_xor(acc[j], m);
    }
    if (g == 0) {
        float inv = (cnt > 0) ? 1.0f / (float)cnt : 0.0f;
        uint4 o;
        o.x = (uint)f2bf(acc[0] * inv) | ((uint)f2bf(acc[1] * inv) << 16);
        o.y = (uint)f2bf(acc[2] * inv) | ((uint)f2bf(acc[3] * inv) << 16);
        o.z = (uint)f2bf(acc[4] * inv) | ((uint)f2bf(acc[5] * inv) << 16);
        o.w = (uint)f2bf(acc[6] * inv) | ((uint)f2bf(acc[7] * inv) << 16);
        ((uint4*)(mean + (size_t)d * D))[gl] = o;
    }
}

// ---------------- fused SAGE MFMA GEMM: C = [mean|self] @ WT^T + b ----------------
// 4 waves, BM=64, each wave owns 16 rows x 128 cols. K=256 (two 128-col sources).
// A staged to LDS via global_load_lds w/ XOR swizzle (linear dest, inv-swz source).

template <bool RELU, bool WF32, bool WBF16>
__global__ __launch_bounds__(256) void sage_mfma(
    const ushort* __restrict__ A1, const ushort* __restrict__ A2,
    const ushort* __restrict__ WT, const float* __restrict__ bias,
    float* __restrict__ Hf, ushort* __restrict__ Hb, int M)
{
    __shared__ __attribute__((aligned(16))) char smem[64 * 512];  // 32 KB: [64 rows][512 B]
    int w = threadIdx.x >> 6, lane = threadIdx.x & 63;
    int row0 = blockIdx.x * 64;

    // each wave stages its own 16 rows (8 KB), 1024 B per iteration
#pragma unroll
    for (int it = 0; it < 8; ++it) {
        int off = w * 8192 + it * 1024 + lane * 16;   // linear LDS byte offset
        int row = off >> 9;
        int colb = off & 511;
        int csrc = colb ^ ((row & 7) << 4);           // inverse-swizzled source col
        int rg = row0 + row; if (rg > M - 1) rg = M - 1;
        const char* src = (csrc < 256)
            ? (const char*)A1 + (size_t)rg * 256 + csrc
            : (const char*)A2 + (size_t)rg * 256 + (csrc - 256);
        __builtin_amdgcn_global_load_lds(
            (const __attribute__((address_space(1))) void*)src,
            (__attribute__((address_space(3))) void*)(smem + w * 8192 + it * 1024),
            16, 0, 0);
    }
    asm volatile("s_waitcnt vmcnt(0)" ::: "memory");   // own-wave data only; no barrier needed

    // A fragments: lane holds A[row = lane&15][k = s*32 + (lane>>4)*8 .. +8]
    bf16x8 a[8];
#pragma unroll
    for (int s = 0; s < 8; ++s) {
        int lin = (w * 16 + (lane & 15)) * 512 + s * 64 + (lane >> 4) * 16;
        int adr = lin ^ ((lane & 7) << 4);            // row&7 == lane&7 (w*16 % 8 == 0)
        a[s] = *reinterpret_cast<const bf16x8*>(smem + adr);
    }

    f32x4 acc[8];
#pragma unroll
    for (int f = 0; f < 8; ++f) acc[f] = (f32x4){0.f, 0.f, 0.f, 0.f};

#pragma unroll
    for (int s = 0; s < 8; ++s) {
#pragma unroll
        for (int f = 0; f < 8; ++f) {
            // B fragment: lane holds WT[col = f*16 + (lane&15)][k = s*32 + (lane>>4)*8 .. +8]
            const ushort* bp = WT + ((f * 16 + (lane & 15)) * 256 + s * 32 + (lane >> 4) * 8);
            bf16x8 b = *reinterpret_cast<const bf16x8*>(bp);
            acc[f] = __builtin_amdgcn_mfma_f32_16x16x32_bf16(a[s], b, acc[f], 0, 0, 0);
        }
    }

    // epilogue: C col = lane&15 (+16f), row = (lane>>4)*4 + r
    int colbase = lane & 15;
    int rquad = lane >> 4;
#pragma unroll
    for (int f = 0; f < 8; ++f) {
        int col = f * 16 + colbase;
        float bj = bias[col];
#pragma unroll
        for (int r = 0; r < 4; ++r) {
            int row = row0 + w * 16 + rquad * 4 + r;
            if (row < M) {
                float v = acc[f][r] + bj;
                if (RELU) v = fmaxf(v, 0.f);
                if (WF32) Hf[(size_t)row * 128 + col] = v;
                if (WBF16) Hb[(size_t)row * 128 + col] = f2bf(v);
            }
        }
    }
}

// ---------------- out_s = h2b @ Ws  (M x 128 @ 128 x 64) ----------------

__global__ __launch_bounds__(256) void out_mfma(
    const ushort* __restrict__ A, const ushort* __restrict__ WsT,
    float* __restrict__ Out, int M)
{
    __shared__ __attribute__((aligned(16))) char smem[64 * 256];  // 16 KB
    int w = threadIdx.x >> 6, lane = threadIdx.x & 63;
    int row0 = blockIdx.x * 64;

#pragma unroll
    for (int it = 0; it < 4; ++it) {
        int off = w * 4096 + it * 1024 + lane * 16;
        int row = off >> 8;
        int colb = off & 255;
        int csrc = colb ^ ((row & 7) << 4);
        int rg = row0 + row; if (rg > M - 1) rg = M - 1;
        __builtin_amdgcn_global_load_lds(
            (const __attribute__((address_space(1))) void*)((const char*)A + (size_t)rg * 256 + csrc),
            (__attribute__((address_space(3))) void*)(smem + w * 4096 + it * 1024),
            16, 0, 0);
    }
    asm volatile("s_waitcnt vmcnt(0)" ::: "memory");

    bf16x8 a[4];
#pragma unroll
    for (int s = 0; s < 4; ++s) {
        int lin = (w * 16 + (lane & 15)) * 256 + s * 64 + (lane >> 4) * 16;
        int adr = lin ^ ((lane & 7) << 4);
        a[s] = *reinterpret_cast<const bf16x8*>(smem + adr);
    }

    f32x4 acc[4];
#pragma unroll
    for (int f = 0; f < 4; ++f) acc[f] = (f32x4){0.f, 0.f, 0.f, 0.f};

#pragma unroll
    for (int s = 0; s < 4; ++s) {
#pragma unroll
        for (int f = 0; f < 4; ++f) {
            const ushort* bp = WsT + ((f * 16 + (lane & 15)) * 128 + s * 32 + (lane >> 4) * 8);
            bf16x8 b = *reinterpret_cast<const bf16x8*>(bp);
            acc[f] = __builtin_amdgcn_mfma_f32_16x16x32_bf16(a[s], b, acc[f], 0, 0, 0);
        }
    }

    int colbase = lane & 15;
    int rquad = lane >> 4;
#pragma unroll
    for (int f = 0; f < 4; ++f) {
        int col = f * 16 + colbase;
#pragma unroll
        for (int r = 0; r < 4; ++r) {
            int row = row0 + w * 16 + rquad * 4 + r;
            if (row < M) Out[(size_t)row * DS + col] = acc[f][r];
        }
    }
}

extern "C" void kernel_launch(void* const* d_in, const int* in_sizes, int n_in,
                              void* d_out, int out_size, void* d_ws, size_t ws_size,
                              hipStream_t stream) {
    const float* x   = (const float*)d_in[0];
    const int*   ei  = (const int*)d_in[1];
    const float* Wl1 = (const float*)d_in[2];
    const float* bl1 = (const float*)d_in[3];
    const float* Wr1 = (const float*)d_in[4];
    const float* Wl2 = (const float*)d_in[5];
    const float* bl2 = (const float*)d_in[6];
    const float* Wr2 = (const float*)d_in[7];
    const float* Ws  = (const float*)d_in[8];

    const int* src = ei;              // edge_index[0]
    const int* dst = ei + E_EDGES;    // edge_index[1]

    char* wsb = (char*)d_ws;
    size_t off = 0;
    auto alloc = [&](size_t bytes) -> void* {
        void* p = wsb + off;
        off = (off + bytes + 255) & ~(size_t)255;
        return p;
    };
    int*    deg    = (int*)alloc(4 * (size_t)(N_NODES + 1));   // +1: counter rides along
    int*    startp = (int*)alloc(4 * (size_t)N_NODES);
    int*    cursor = (int*)alloc(4 * (size_t)N_NODES);
    int*    esrc   = (int*)alloc(4 * (size_t)E_EDGES);
    ushort* xb     = (ushort*)alloc(2 * (size_t)N_NODES * D);
    ushort* meanb  = (ushort*)alloc(2 * (size_t)N_NODES * D);
    ushort* h1b    = (ushort*)alloc(2 * (size_t)N_NODES * D);
    ushort* h2b    = (ushort*)alloc(2 * (size_t)N_NODES * D);
    ushort* WT1    = (ushort*)alloc(2 * 128 * 256);
    ushort* WT2    = (ushort*)alloc(2 * 128 * 256);
    ushort* WsT    = (ushort*)alloc(2 * 64 * 128);
    int* counter = deg + N_NODES;

    float* out_s = (float*)d_out;
    float* h2    = (float*)d_out + (size_t)N_NODES * DS;

    // segment build (zero deg + counter in one memset)
    hipMemsetAsync(deg, 0, 4 * (size_t)(N_NODES + 1), stream);
    degree_kernel<<<(E_EDGES + 255) / 256, 256, 0, stream>>>(dst, deg, E_EDGES);
    assign_kernel<<<(N_NODES + 255) / 256, 256, 0, stream>>>(deg, startp, cursor, counter, N_NODES);
    fill_kernel<<<(E_EDGES + 255) / 256, 256, 0, stream>>>(src, dst, cursor, esrc, E_EDGES);

    // dtype prep
    f32_to_bf16_kernel<<<2048, 256, 0, stream>>>(x, xb, N_NODES * D / 4);
    transpose_weights<<<(73728 + 255) / 256, 256, 0, stream>>>(
        Wl1, Wr1, Wl2, Wr2, Ws, WT1, WT2, WsT);

    const int GB = (N_NODES + 63) / 64;   // 782 GEMM blocks

    // layer 1
    aggregate_mean_bf16<<<(N_NODES + 3) / 4, 256, 0, stream>>>(xb, startp, deg, esrc, meanb, N_NODES);
    sage_mfma<true, false, true><<<GB, 256, 0, stream>>>(
        meanb, xb, WT1, bl1, nullptr, h1b, N_NODES);

    // layer 2
    aggregate_mean_bf16<<<(N_NODES + 3) / 4, 256, 0, stream>>>(h1b, startp, deg, esrc, meanb, N_NODES);
    sage_mfma<false, true, true><<<GB, 256, 0, stream>>>(
        meanb, h1b, WT2, bl2, h2, h2b, N_NODES);

    // out_s
    out_mfma<<<GB, 256, 0, stream>>>(h2b, WsT, out_s, N_NODES);
}

// Round 4
// 236.587 us; speedup vs baseline: 2.4106x; 1.0485x over previous
//
#include <hip/hip_runtime.h>

#define N_NODES 50000
#define E_EDGES 640000
#define D 128
#define DS 64
#define NTILES 3125   // 50000 / 16 exactly

typedef __bf16 bf16x8 __attribute__((ext_vector_type(8)));
typedef float f32x4 __attribute__((ext_vector_type(4)));

static __device__ __forceinline__ ushort f2bf(float f) {
    uint u = __float_as_uint(f);
    uint r = u + 0x7fffu + ((u >> 16) & 1u);
    return (ushort)(r >> 16);
}

// ---------------- segment build ----------------

__global__ void zero_kernel(int* __restrict__ p, int n) {
    int i = blockIdx.x * blockDim.x + threadIdx.x;
    if (i < n) p[i] = 0;
}

__global__ void degree_kernel(const int* __restrict__ dst, int* __restrict__ deg, int e) {
    int i = blockIdx.x * blockDim.x + threadIdx.x;
    if (i < e) atomicAdd(&deg[dst[i]], 1);
}

// start[i] = disjoint segment base (order unimportant); cursor[i] = start[i]
__global__ void assign_kernel(const int* __restrict__ deg, int* __restrict__ start,
                              int* __restrict__ cursor, int* __restrict__ counter, int n) {
    int i = blockIdx.x * blockDim.x + threadIdx.x;
    int lane = threadIdx.x & 63;
    int v = (i < n) ? deg[i] : 0;
    int s = v;
#pragma unroll
    for (int off = 1; off < 64; off <<= 1) {
        int t = __shfl_up(s, off);
        if (lane >= off) s += t;
    }
    int total = __shfl(s, 63);
    int base = 0;
    if (lane == 63) base = atomicAdd(counter, total);
    base = __shfl(base, 63);
    int ex = base + s - v;    // exclusive within wave
    if (i < n) { start[i] = ex; cursor[i] = ex; }
}

__global__ void fill_kernel(const int* __restrict__ src, const int* __restrict__ dst,
                            int* __restrict__ cursor, int* __restrict__ esrc, int e) {
    int i = blockIdx.x * blockDim.x + threadIdx.x;
    if (i < e) {
        int pos = atomicAdd(&cursor[dst[i]], 1);
        esrc[pos] = src[i];
    }
}

// ---------------- conversions ----------------

__global__ void f32_to_bf16_kernel(const float* __restrict__ in, ushort* __restrict__ out, int n4) {
    int i = blockIdx.x * blockDim.x + threadIdx.x;
    int stride = gridDim.x * blockDim.x;
    for (; i < n4; i += stride) {
        float4 v = ((const float4*)in)[i];
        ushort4 o;
        o.x = f2bf(v.x); o.y = f2bf(v.y); o.z = f2bf(v.z); o.w = f2bf(v.w);
        ((ushort4*)out)[i] = o;
    }
}

// Fragment-major weight layouts.
// WTf: for fragment (f=col/16, s=k/32): F = f*8+s; lane l = (n&15) | (((k>>3)&3)<<4);
//      element (n,k) -> WTf[(F*64+l)*8 + (k&7)].  64 KB, each fragment 1 KB contiguous.
// WsTf: F = (m>>4)*4 + (k>>5); same inner mapping.  16 KB.
__global__ void transpose_weights(const float* __restrict__ Wl1, const float* __restrict__ Wr1,
                                  const float* __restrict__ Wl2, const float* __restrict__ Wr2,
                                  const float* __restrict__ Ws,
                                  ushort* __restrict__ WT1f, ushort* __restrict__ WT2f,
                                  ushort* __restrict__ WsTf) {
    int i = blockIdx.x * blockDim.x + threadIdx.x;
    if (i < 32768) {
        int n = i >> 8, k = i & 255;
        float v = (k < 128) ? Wl1[k * 128 + n] : Wr1[(k - 128) * 128 + n];
        int F = (n >> 4) * 8 + (k >> 5);
        int l = (n & 15) | (((k >> 3) & 3) << 4);
        WT1f[(F * 64 + l) * 8 + (k & 7)] = f2bf(v);
    } else if (i < 65536) {
        int j = i - 32768;
        int n = j >> 8, k = j & 255;
        float v = (k < 128) ? Wl2[k * 128 + n] : Wr2[(k - 128) * 128 + n];
        int F = (n >> 4) * 8 + (k >> 5);
        int l = (n & 15) | (((k >> 3) & 3) << 4);
        WT2f[(F * 64 + l) * 8 + (k & 7)] = f2bf(v);
    } else if (i < 73728) {
        int j = i - 65536;
        int m = j >> 7, k = j & 127;
        int F = (m >> 4) * 4 + (k >> 5);
        int l = (m & 15) | (((k >> 3) & 3) << 4);
        WsTf[(F * 64 + l) * 8 + (k & 7)] = f2bf(Ws[k * 64 + m]);
    }
}

// ---------------- segment mean, bf16 in/out ----------------
// one wave per dst node; 16 lanes x 16B cover a 256B row; 4 edges in flight per iter

__global__ void aggregate_mean_bf16(const ushort* __restrict__ feat, const int* __restrict__ start,
                                    const int* __restrict__ deg, const int* __restrict__ esrc,
                                    ushort* __restrict__ mean, int n) {
    int wid = threadIdx.x >> 6;           // 4 waves per block
    int lane = threadIdx.x & 63;
    int d = blockIdx.x * 4 + wid;
    if (d >= n) return;
    int beg = start[d], cnt = deg[d];
    int g = lane >> 4;                    // edge group 0..3
    int gl = lane & 15;                   // 16B chunk within row

    float acc[8] = {0.f, 0.f, 0.f, 0.f, 0.f, 0.f, 0.f, 0.f};
    for (int i = 0; i < cnt; i += 4) {
        int idx = i + g;
        if (idx < cnt) {
            int e = esrc[beg + idx];
            uint4 v = ((const uint4*)(feat + (size_t)e * D))[gl];
            acc[0] += __uint_as_float(v.x << 16);
            acc[1] += __uint_as_float(v.x & 0xffff0000u);
            acc[2] += __uint_as_float(v.y << 16);
            acc[3] += __uint_as_float(v.y & 0xffff0000u);
            acc[4] += __uint_as_float(v.z << 16);
            acc[5] += __uint_as_float(v.z & 0xffff0000u);
            acc[6] += __uint_as_float(v.w << 16);
            acc[7] += __uint_as_float(v.w & 0xffff0000u);
        }
    }
#pragma unroll
    for (int m = 16; m <= 32; m <<= 1) {
#pragma unroll
        for (int j = 0; j < 8; ++j) acc[j] += __shfl_xor(acc[j], m);
    }
    if (g == 0) {
        float inv = (cnt > 0) ? 1.0f / (float)cnt : 0.0f;
        uint4 o;
        o.x = (uint)f2bf(acc[0] * inv) | ((uint)f2bf(acc[1] * inv) << 16);
        o.y = (uint)f2bf(acc[2] * inv) | ((uint)f2bf(acc[3] * inv) << 16);
        o.z = (uint)f2bf(acc[4] * inv) | ((uint)f2bf(acc[5] * inv) << 16);
        o.w = (uint)f2bf(acc[6] * inv) | ((uint)f2bf(acc[7] * inv) << 16);
        ((uint4*)(mean + (size_t)d * D))[gl] = o;
    }
}

// ---------------- fused SAGE MFMA GEMM: C = [mean|self] @ WT^T + b ----------------
// 512 threads (8 waves). WTf (64 KB, fragment-major) staged linearly into LDS once.
// Each wave grid-strides over 16-row tiles: A direct global->reg (prefetched),
// B conflict-free ds_read_b128, 64 MFMA, epilogue store.

template <bool RELU, bool WF32, bool WBF16>
__global__ __launch_bounds__(512) void sage_mfma(
    const ushort* __restrict__ A1, const ushort* __restrict__ A2,
    const ushort* __restrict__ WTf, const float* __restrict__ bias,
    float* __restrict__ Hf, ushort* __restrict__ Hb)
{
    __shared__ __attribute__((aligned(16))) char smem[65536];
    int w = threadIdx.x >> 6, lane = threadIdx.x & 63;

    // stage WTf linearly (dest = wave-uniform base + lane*16, src identical layout)
#pragma unroll
    for (int it = 0; it < 8; ++it) {
        int off = w * 8192 + it * 1024;
        __builtin_amdgcn_global_load_lds(
            (const __attribute__((address_space(1))) void*)((const char*)WTf + off + lane * 16),
            (__attribute__((address_space(3))) void*)(smem + off), 16, 0, 0);
    }

    int rl = lane & 15;       // A row within tile / C col within 16
    int kg = lane >> 4;       // k-subgroup

    float bj[8];
#pragma unroll
    for (int f = 0; f < 8; ++f) bj[f] = bias[f * 16 + rl];

    int tile = blockIdx.x * 8 + w;
    const int stride = gridDim.x * 8;

    bf16x8 aCur[8], aNxt[8];
    auto loadA = [&](int t, bf16x8* a) {
        const ushort* r1 = A1 + (size_t)(t * 16 + rl) * 128 + kg * 8;
        const ushort* r2 = A2 + (size_t)(t * 16 + rl) * 128 + kg * 8;
#pragma unroll
        for (int s = 0; s < 4; ++s) a[s] = *reinterpret_cast<const bf16x8*>(r1 + s * 32);
#pragma unroll
        for (int s = 0; s < 4; ++s) a[4 + s] = *reinterpret_cast<const bf16x8*>(r2 + s * 32);
    };

    if (tile < NTILES) loadA(tile, aCur);
    __syncthreads();          // drains staging (and first A loads)

    for (; tile < NTILES; tile += stride) {
        int nt = tile + stride;
        if (nt < NTILES) loadA(nt, aNxt);

        f32x4 acc[8];
#pragma unroll
        for (int f = 0; f < 8; ++f) acc[f] = (f32x4){0.f, 0.f, 0.f, 0.f};

#pragma unroll
        for (int s = 0; s < 8; ++s) {
#pragma unroll
            for (int f = 0; f < 8; ++f) {
                bf16x8 b = *reinterpret_cast<const bf16x8*>(smem + ((f * 8 + s) * 64 + lane) * 16);
                acc[f] = __builtin_amdgcn_mfma_f32_16x16x32_bf16(aCur[s], b, acc[f], 0, 0, 0);
            }
        }

        int rowb = tile * 16 + kg * 4;
#pragma unroll
        for (int f = 0; f < 8; ++f) {
            int col = f * 16 + rl;
#pragma unroll
            for (int r = 0; r < 4; ++r) {
                float v = acc[f][r] + bj[f];
                if (RELU) v = fmaxf(v, 0.f);
                size_t o = (size_t)(rowb + r) * 128 + col;
                if (WF32) Hf[o] = v;
                if (WBF16) Hb[o] = f2bf(v);
            }
        }
#pragma unroll
        for (int s = 0; s < 8; ++s) aCur[s] = aNxt[s];
    }
}

// ---------------- out_s = h2b @ Ws  (M x 128 @ 128 x 64), Ws fragments in registers ----------------

__global__ __launch_bounds__(256) void out_mfma(
    const ushort* __restrict__ A, const ushort* __restrict__ WsTf,
    float* __restrict__ Out)
{
    int w = threadIdx.x >> 6, lane = threadIdx.x & 63;
    int rl = lane & 15, kg = lane >> 4;

    bf16x8 wsf[16];
#pragma unroll
    for (int F = 0; F < 16; ++F)
        wsf[F] = *reinterpret_cast<const bf16x8*>(WsTf + (F * 64 + lane) * 8);

    int tile = blockIdx.x * 4 + w;
    const int stride = gridDim.x * 4;

    bf16x8 aCur[4], aNxt[4];
    auto loadA = [&](int t, bf16x8* a) {
        const ushort* r = A + (size_t)(t * 16 + rl) * 128 + kg * 8;
#pragma unroll
        for (int s = 0; s < 4; ++s) a[s] = *reinterpret_cast<const bf16x8*>(r + s * 32);
    };
    if (tile < NTILES) loadA(tile, aCur);

    for (; tile < NTILES; tile += stride) {
        int nt = tile + stride;
        if (nt < NTILES) loadA(nt, aNxt);

        f32x4 acc[4];
#pragma unroll
        for (int f = 0; f < 4; ++f) acc[f] = (f32x4){0.f, 0.f, 0.f, 0.f};

#pragma unroll
        for (int s = 0; s < 4; ++s) {
#pragma unroll
            for (int f = 0; f < 4; ++f)
                acc[f] = __builtin_amdgcn_mfma_f32_16x16x32_bf16(aCur[s], wsf[f * 4 + s], acc[f], 0, 0, 0);
        }

        int rowb = tile * 16 + kg * 4;
#pragma unroll
        for (int f = 0; f < 4; ++f) {
            int col = f * 16 + rl;
#pragma unroll
            for (int r = 0; r < 4; ++r)
                Out[(size_t)(rowb + r) * DS + col] = acc[f][r];
        }
#pragma unroll
        for (int s = 0; s < 4; ++s) aCur[s] = aNxt[s];
    }
}

extern "C" void kernel_launch(void* const* d_in, const int* in_sizes, int n_in,
                              void* d_out, int out_size, void* d_ws, size_t ws_size,
                              hipStream_t stream) {
    const float* x   = (const float*)d_in[0];
    const int*   ei  = (const int*)d_in[1];
    const float* Wl1 = (const float*)d_in[2];
    const float* bl1 = (const float*)d_in[3];
    const float* Wr1 = (const float*)d_in[4];
    const float* Wl2 = (const float*)d_in[5];
    const float* bl2 = (const float*)d_in[6];
    const float* Wr2 = (const float*)d_in[7];
    const float* Ws  = (const float*)d_in[8];

    const int* src = ei;              // edge_index[0]
    const int* dst = ei + E_EDGES;    // edge_index[1]

    char* wsb = (char*)d_ws;
    size_t off = 0;
    auto alloc = [&](size_t bytes) -> void* {
        void* p = wsb + off;
        off = (off + bytes + 255) & ~(size_t)255;
        return p;
    };
    int*    deg    = (int*)alloc(4 * (size_t)(N_NODES + 1));   // +1: counter rides along
    int*    startp = (int*)alloc(4 * (size_t)N_NODES);
    int*    cursor = (int*)alloc(4 * (size_t)N_NODES);
    int*    esrc   = (int*)alloc(4 * (size_t)E_EDGES);
    ushort* xb     = (ushort*)alloc(2 * (size_t)N_NODES * D);
    ushort* meanb  = (ushort*)alloc(2 * (size_t)N_NODES * D);
    ushort* h1b    = (ushort*)alloc(2 * (size_t)N_NODES * D);
    ushort* h2b    = (ushort*)alloc(2 * (size_t)N_NODES * D);
    ushort* WT1f   = (ushort*)alloc(2 * 128 * 256);
    ushort* WT2f   = (ushort*)alloc(2 * 128 * 256);
    ushort* WsTf   = (ushort*)alloc(2 * 64 * 128);
    int* counter = deg + N_NODES;

    float* out_s = (float*)d_out;
    float* h2    = (float*)d_out + (size_t)N_NODES * DS;

    // segment build
    zero_kernel<<<(N_NODES + 256) / 256, 256, 0, stream>>>(deg, N_NODES + 1);
    degree_kernel<<<(E_EDGES + 255) / 256, 256, 0, stream>>>(dst, deg, E_EDGES);
    assign_kernel<<<(N_NODES + 255) / 256, 256, 0, stream>>>(deg, startp, cursor, counter, N_NODES);
    fill_kernel<<<(E_EDGES + 255) / 256, 256, 0, stream>>>(src, dst, cursor, esrc, E_EDGES);

    // dtype prep
    f32_to_bf16_kernel<<<2048, 256, 0, stream>>>(x, xb, N_NODES * D / 4);
    transpose_weights<<<(73728 + 255) / 256, 256, 0, stream>>>(
        Wl1, Wr1, Wl2, Wr2, Ws, WT1f, WT2f, WsTf);

    // layer 1
    aggregate_mean_bf16<<<(N_NODES + 3) / 4, 256, 0, stream>>>(xb, startp, deg, esrc, meanb, N_NODES);
    sage_mfma<true, false, true><<<256, 512, 0, stream>>>(
        meanb, xb, WT1f, bl1, nullptr, h1b);

    // layer 2
    aggregate_mean_bf16<<<(N_NODES + 3) / 4, 256, 0, stream>>>(h1b, startp, deg, esrc, meanb, N_NODES);
    sage_mfma<false, true, true><<<256, 512, 0, stream>>>(
        meanb, h1b, WT2f, bl2, h2, h2b);

    // out_s
    out_mfma<<<512, 256, 0, stream>>>(h2b, WsTf, out_s);
}